// Round 1
// 441.656 us; speedup vs baseline: 1.0348x; 1.0348x over previous
//
#include <hip/hip_runtime.h>
#include <hip/hip_bf16.h>
#include <math.h>

// ---------------- dims ----------------
#define B 256
#define FC1_K   55815
#define FC1_N   120
#define FC2_N   84
#define KP        57344
#define FC1_SPLIT 128
#define FC1_KC    (KP / FC1_SPLIT)

typedef __attribute__((ext_vector_type(8))) short bf16x8;
typedef __attribute__((ext_vector_type(4))) float f32x4;

static __device__ __forceinline__ unsigned short bf16_bits(float f) {
    __hip_bfloat16 h = __float2bfloat16(f);
    return *(unsigned short*)&h;
}

// async global->LDS copy, 4 B per lane; lds base must be wave-uniform
#define ASYNC_CP(g, l) __builtin_amdgcn_global_load_lds( \
    (const __attribute__((address_space(1))) void*)(g),  \
    (__attribute__((address_space(3))) void*)(l), 4, 0, 0)

// ======== fused prep: conv-weight relayout + fc1_w->bf16 (incl. all pads) ===
// grid (KP/256, 128). Replaces {memset(W), memset(zeros), wprep, wconv}.
__global__ __launch_bounds__(256) void prep_kernel(
    const float* __restrict__ w1, const float* __restrict__ w2,
    const float* __restrict__ fc1_w,
    float* __restrict__ w1p, float* __restrict__ w2p,
    float* __restrict__ zeros, unsigned short* __restrict__ wb) {
    const int n = blockIdx.y;                       // 0..127 (N-pad rows >=120)
    const int k = blockIdx.x * 256 + threadIdx.x;   // 0..KP-1 (K-pad >= FC1_K)
    unsigned short v = 0;
    if (n < FC1_N && k < FC1_K) v = bf16_bits(fc1_w[(size_t)n * FC1_K + k]);
    wb[(size_t)n * KP + k] = v;

    if (blockIdx.x == 0 && n == 0) {
        int t = threadIdx.x;
        for (int f = t; f < 450; f += 256) {
            int o = f % 6, tap = f / 6;
            int kx = tap % 5, r2 = tap / 5, ky = r2 % 5, c = r2 / 5;
            w1p[f] = w1[(o * 3 + c) * 25 + ky * 5 + kx];
        }
        for (int f = t; f < 810; f += 256) {
            int o = f % 15, tap = f / 15;
            int kx = tap % 3, r2 = tap / 3, ky = r2 % 3, c = r2 / 3;
            w2p[f] = w2[(o * 6 + c) * 9 + ky * 3 + kx];
        }
        if (t < 64) zeros[t] = 0.f;                 // 256-B OOB source
    }
}

// ======== conv1 (5x5 s2 p1) + ReLU + pool(2,1) -> padded bf16 pool1 ========
// pool1 layout: (B, 6, 123, 128) bf16, col idx = px+1 (left pad), pads = 0.
// Block 256 = 32 colgroups x 8 conv rows. Grid (18 y-bands, 256 batch).
__global__ __launch_bounds__(256) void conv1_pool1_kernel(
    const float* __restrict__ x, const float* __restrict__ w1p,
    const float* __restrict__ b1, unsigned short* __restrict__ pool1,
    const float* __restrict__ zeros) {
    __shared__ __align__(16) float in_t[19 * 256 + 8];
    __shared__ __align__(16) unsigned short out_t[6 * 8 * 132];

    const int tid = threadIdx.x;
    const int wave = tid >> 6, lane = tid & 63;
    const int PB = 7 * blockIdx.x;          // pool row base
    const int b  = blockIdx.y;
    const int cg = tid & 31, rr = tid >> 5; // col group (4 cols), conv row 0..7
    const int iyb = 2 * PB - 1;

    float acc[4][6];
    #pragma unroll
    for (int j = 0; j < 4; ++j)
        #pragma unroll
        for (int o = 0; o < 6; ++o) acc[j][o] = b1[o];

    for (int c = 0; c < 3; ++c) {
        __syncthreads();                       // prev channel compute done
        const float* xp = x + (size_t)(b * 3 + c) * 62500;
        #pragma unroll
        for (int i = 0; i < 19; ++i) {
            int chunk = wave * 19 + i;         // 76 chunks of 64 floats
            int f = chunk * 64 + lane;
            int row = f >> 8, m = f & 255;
            int iy = iyb + row, col = m - 1;
            const float* g = ((unsigned)iy < 250u && (unsigned)col < 250u)
                             ? (xp + iy * 250 + col) : zeros;
            ASYNC_CP(g, &in_t[chunk * 64]);
        }
        __syncthreads();                       // drains vmcnt (async copies)
        const float* wc = w1p + c * 150;       // uniform -> s_load
        #pragma unroll
        for (int ky = 0; ky < 5; ++ky) {
            const float* rp = &in_t[(2 * rr + ky) * 256 + 8 * cg];
            float f[12];
            float4 v0 = *(const float4*)rp;
            float4 v1 = *(const float4*)(rp + 4);
            float4 v2 = *(const float4*)(rp + 8);
            f[0]=v0.x; f[1]=v0.y; f[2]=v0.z; f[3]=v0.w;
            f[4]=v1.x; f[5]=v1.y; f[6]=v1.z; f[7]=v1.w;
            f[8]=v2.x; f[9]=v2.y; f[10]=v2.z; f[11]=v2.w;
            #pragma unroll
            for (int kx = 0; kx < 5; ++kx) {
                const float* wp = wc + (ky * 5 + kx) * 6;  // uniform
                #pragma unroll
                for (int j = 0; j < 4; ++j) {
                    float xv = f[2 * j + kx];
                    #pragma unroll
                    for (int o = 0; o < 6; ++o) acc[j][o] += xv * wp[o];
                }
            }
        }
    }
    // write conv+ReLU tile as bf16
    #pragma unroll
    for (int o = 0; o < 6; ++o) {
        unsigned short h0 = bf16_bits(fmaxf(acc[0][o], 0.f));
        unsigned short h1 = bf16_bits(fmaxf(acc[1][o], 0.f));
        unsigned short h2 = bf16_bits(fmaxf(acc[2][o], 0.f));
        unsigned short h3 = bf16_bits(fmaxf(acc[3][o], 0.f));
        uint2 pk;
        pk.x = (unsigned)h0 | ((unsigned)h1 << 16);
        pk.y = (unsigned)h2 | ((unsigned)h3 << 16);
        *(uint2*)&out_t[(o * 8 + rr) * 132 + 4 * cg] = pk;
    }
    __syncthreads();
    // pool 2x2 s1 (integer max on non-negative bf16 bits), write padded pool1
    for (int it = tid; it < 6 * 7 * 32; it += 256) {
        int g = it & 31, rem = it >> 5;
        int pyl = rem % 7, oc = rem / 7;
        int py = PB + pyl;
        if (py >= 123) continue;
        const unsigned short* q0 = &out_t[(oc * 8 + pyl) * 132 + 4 * g];
        const unsigned short* q1 = q0 + 132;
        uint2 ua = *(const uint2*)q0;
        uint2 ub = *(const uint2*)q1;
        unsigned short va[5] = {(unsigned short)(ua.x & 0xffff), (unsigned short)(ua.x >> 16),
                                (unsigned short)(ua.y & 0xffff), (unsigned short)(ua.y >> 16), q0[4]};
        unsigned short vb[5] = {(unsigned short)(ub.x & 0xffff), (unsigned short)(ub.x >> 16),
                                (unsigned short)(ub.y & 0xffff), (unsigned short)(ub.y >> 16), q1[4]};
        unsigned short* dst = pool1 + ((size_t)(b * 6 + oc) * 123 + py) * 128;
        #pragma unroll
        for (int j = 0; j < 4; ++j) {
            int px = 4 * g + j;
            if (px >= 127) continue;
            unsigned short m = 0;
            if (px <= 122) {
                unsigned short m0 = va[j] > va[j+1] ? va[j] : va[j+1];
                unsigned short m1 = vb[j] > vb[j+1] ? vb[j] : vb[j+1];
                m = m0 > m1 ? m0 : m1;
            }
            dst[1 + px] = m;
        }
        if (g == 0) dst[0] = 0;
    }
}

// ======== conv2 (3x3 s2 p1) + ReLU + pool(2,1) -> bf16 A rows ========
// Block 128 = 16 colgroups x 8 conv rows. Grid (9 y-bands, 256 batch).
__global__ __launch_bounds__(128) void conv2_pool2_kernel(
    const unsigned short* __restrict__ pool1, const float* __restrict__ w2p,
    const float* __restrict__ b2, unsigned short* __restrict__ A,
    const unsigned int* __restrict__ zerosu) {
    __shared__ __align__(16) unsigned int in2[17 * 64 + 4];
    __shared__ __align__(16) unsigned short out2[15 * 8 * 68];

    const int tid = threadIdx.x;
    const int wave = tid >> 6, lane = tid & 63;
    const int PB = 7 * blockIdx.x;
    const int b  = blockIdx.y;
    const int cg = tid & 15, rr = tid >> 4;
    const int iyb = 2 * PB - 1;

    float acc[4][15];
    #pragma unroll
    for (int j = 0; j < 4; ++j)
        #pragma unroll
        for (int o = 0; o < 15; ++o) acc[j][o] = b2[o];

    const unsigned int* p1u = (const unsigned int*)pool1;
    for (int c = 0; c < 6; ++c) {
        __syncthreads();
        const unsigned int* pp = p1u + (size_t)(b * 6 + c) * (123 * 64);
        #pragma unroll
        for (int i = 0; i < 9; ++i) {
            int chunk = wave * 9 + i;          // 17 chunks of 64 u32
            if (chunk < 17) {
                int f = chunk * 64 + lane;
                int row = f >> 6, off = f & 63;
                int iy = iyb + row;
                const unsigned int* g = ((unsigned)iy < 123u)
                                        ? (pp + iy * 64 + off) : zerosu;
                ASYNC_CP(g, &in2[chunk * 64]);
            }
        }
        __syncthreads();
        #pragma unroll
        for (int ky = 0; ky < 3; ++ky) {
            const unsigned int* rp = &in2[(2 * rr + ky) * 64 + 4 * cg];
            uint4 u4 = *(const uint4*)rp;
            unsigned int u5 = rp[4];
            float f[10];
            f[0] = __uint_as_float(u4.x << 16); f[1] = __uint_as_float(u4.x & 0xffff0000u);
            f[2] = __uint_as_float(u4.y << 16); f[3] = __uint_as_float(u4.y & 0xffff0000u);
            f[4] = __uint_as_float(u4.z << 16); f[5] = __uint_as_float(u4.z & 0xffff0000u);
            f[6] = __uint_as_float(u4.w << 16); f[7] = __uint_as_float(u4.w & 0xffff0000u);
            f[8] = __uint_as_float(u5  << 16);  f[9] = __uint_as_float(u5  & 0xffff0000u);
            #pragma unroll
            for (int kx = 0; kx < 3; ++kx) {
                const float* wp = w2p + (c * 9 + ky * 3 + kx) * 15;  // uniform
                #pragma unroll
                for (int j = 0; j < 4; ++j) {
                    float xv = f[2 * j + kx];
                    #pragma unroll
                    for (int o = 0; o < 15; ++o) acc[j][o] += xv * wp[o];
                }
            }
        }
    }
    #pragma unroll
    for (int o = 0; o < 15; ++o) {
        unsigned short h0 = bf16_bits(fmaxf(acc[0][o], 0.f));
        unsigned short h1 = bf16_bits(fmaxf(acc[1][o], 0.f));
        unsigned short h2 = bf16_bits(fmaxf(acc[2][o], 0.f));
        unsigned short h3 = bf16_bits(fmaxf(acc[3][o], 0.f));
        uint2 pk;
        pk.x = (unsigned)h0 | ((unsigned)h1 << 16);
        pk.y = (unsigned)h2 | ((unsigned)h3 << 16);
        *(uint2*)&out2[(o * 8 + rr) * 68 + 4 * cg] = pk;
    }
    __syncthreads();
    for (int it = tid; it < 15 * 7 * 16; it += 128) {
        int g = it & 15, rem = it >> 4;
        int pyl = rem % 7, oc = rem / 7;
        int py = PB + pyl;
        if (py >= 61) continue;
        const unsigned short* q0 = &out2[(oc * 8 + pyl) * 68 + 4 * g];
        const unsigned short* q1 = q0 + 68;
        uint2 ua = *(const uint2*)q0;
        uint2 ub = *(const uint2*)q1;
        unsigned short va[5] = {(unsigned short)(ua.x & 0xffff), (unsigned short)(ua.x >> 16),
                                (unsigned short)(ua.y & 0xffff), (unsigned short)(ua.y >> 16), q0[4]};
        unsigned short vb[5] = {(unsigned short)(ub.x & 0xffff), (unsigned short)(ub.x >> 16),
                                (unsigned short)(ub.y & 0xffff), (unsigned short)(ub.y >> 16), q1[4]};
        #pragma unroll
        for (int j = 0; j < 4; ++j) {
            int px = 4 * g + j;
            if (px < 61) {
                unsigned short m0 = va[j] > va[j+1] ? va[j] : va[j+1];
                unsigned short m1 = vb[j] > vb[j+1] ? vb[j] : vb[j+1];
                unsigned short m = m0 > m1 ? m0 : m1;
                A[(size_t)b * KP + (oc * 61 + py) * 61 + px] = m;
            }
        }
    }
}

// ================= fc1: bf16 MFMA split-K GEMM -> fp32 partials ===========
__global__ __launch_bounds__(256) void fc1_mfma_kernel(
    const __hip_bfloat16* __restrict__ A, const __hip_bfloat16* __restrict__ W,
    float* __restrict__ partial) {
    const int wave = threadIdx.x >> 6, lane = threadIdx.x & 63;
    const int mrow = lane & 15, quad = lane >> 4;
    const int m0 = blockIdx.x * 128 + wave * 32;
    const int k0 = blockIdx.y * FC1_KC;

    f32x4 acc[2][8];
    #pragma unroll
    for (int i = 0; i < 2; ++i)
        #pragma unroll
        for (int j = 0; j < 8; ++j) acc[i][j] = (f32x4){0.f, 0.f, 0.f, 0.f};

    const short* Ap = (const short*)A;
    const short* Wp = (const short*)W;
    for (int ks = 0; ks < FC1_KC; ks += 32) {
        const int kk = k0 + ks + quad * 8;
        const bf16x8 a0 = *(const bf16x8*)(Ap + (size_t)(m0 + mrow) * KP + kk);
        const bf16x8 a1 = *(const bf16x8*)(Ap + (size_t)(m0 + 16 + mrow) * KP + kk);
        #pragma unroll
        for (int nt = 0; nt < 8; ++nt) {
            const bf16x8 bb = *(const bf16x8*)(Wp + (size_t)(nt * 16 + mrow) * KP + kk);
            acc[0][nt] = __builtin_amdgcn_mfma_f32_16x16x32_bf16(a0, bb, acc[0][nt], 0, 0, 0);
            acc[1][nt] = __builtin_amdgcn_mfma_f32_16x16x32_bf16(a1, bb, acc[1][nt], 0, 0, 0);
        }
    }
    float* po = partial + (size_t)blockIdx.y * (256 * 128);
    #pragma unroll
    for (int mt = 0; mt < 2; ++mt)
        #pragma unroll
        for (int nt = 0; nt < 8; ++nt)
            #pragma unroll
            for (int r = 0; r < 4; ++r)
                po[(m0 + mt * 16 + quad * 4 + r) * 128 + nt * 16 + mrow] = acc[mt][nt][r];
}

// ====== tail: split-K reduce + bias/ReLU, fc2, fc3, quantum head, softmax ==
// 256 threads: split-K reduction is 2-way parallel over the 128 partials.
__global__ __launch_bounds__(256) void tail_kernel(
    const float* __restrict__ partial, const float* __restrict__ fc1_b,
    const float* __restrict__ fc2_w, const float* __restrict__ fc2_b,
    const float* __restrict__ fc3_w, const float* __restrict__ fc3_b,
    const float* __restrict__ qw, float* __restrict__ out) {
    __shared__ float h1p[2][FC1_N];
    __shared__ float h1[FC1_N];
    __shared__ float h2[FC2_N];
    __shared__ float ang[4];
    int b = blockIdx.x;
    int t = threadIdx.x;
    int grp = t >> 7, tt = t & 127;

    if (tt < FC1_N) {
        const float* p = partial + b * 128 + tt;
        float sum = 0.f;
        #pragma unroll 4
        for (int s = grp * 64; s < grp * 64 + 64; ++s) sum += p[(size_t)s * (256 * 128)];
        h1p[grp][tt] = sum;
    }
    __syncthreads();
    if (t < FC1_N) h1[t] = fmaxf(h1p[0][t] + h1p[1][t] + fc1_b[t], 0.f);
    __syncthreads();
    if (t < FC2_N) {
        float acc = fc2_b[t];
        const float* w = fc2_w + t * FC1_N;
        for (int k = 0; k < FC1_N; ++k) acc += h1[k] * w[k];
        h2[t] = fmaxf(acc, 0.f);
    }
    __syncthreads();
    if (t < 4) {
        float acc = fc3_b[t];
        const float* w = fc3_w + t * FC2_N;
        for (int k = 0; k < FC2_N; ++k) acc += h2[k] * w[k];
        ang[t] = acc;
    }
    __syncthreads();
    if (t == 0) {
        float sr[16], si[16];
        #pragma unroll
        for (int i = 0; i < 16; ++i) { sr[i] = 0.f; si[i] = 0.f; }
        sr[0] = 1.f;
        for (int q = 0; q < 4; ++q) {
            float th = ang[q] * 0.5f;
            float c = cosf(th), s = sinf(th);
            int mask = 1 << (3 - q);
            #pragma unroll
            for (int i = 0; i < 16; ++i) {
                if (i & mask) continue;
                int i1 = i | mask;
                float a0r = sr[i], a0i = si[i], a1r = sr[i1], a1i = si[i1];
                sr[i]  = c * a0r + s * a1i;
                si[i]  = c * a0i - s * a1r;
                sr[i1] = c * a1r + s * a0i;
                si[i1] = c * a1i - s * a0r;
            }
        }
        int widx = 0;
        for (int d = 0; d < 2; ++d) {
            for (int q = 0; q < 4; ++q) {
                float th = qw[widx++] * 0.5f;
                float c = cosf(th), s = sinf(th);
                int mask = 1 << (3 - q);
                #pragma unroll
                for (int i = 0; i < 16; ++i) {
                    if (i & mask) continue;
                    int i1 = i | mask;
                    float a0r = sr[i], a0i = si[i], a1r = sr[i1], a1i = si[i1];
                    sr[i]  = c * a0r - s * a1r;
                    si[i]  = c * a0i - s * a1i;
                    sr[i1] = s * a0r + c * a1r;
                    si[i1] = s * a0i + c * a1i;
                }
            }
            for (int q = 0; q < 3; ++q) {
                int m1 = 1 << (3 - q), m2 = 1 << (2 - q);
                #pragma unroll
                for (int i = 0; i < 16; ++i) {
                    if ((i & m1) && (i & m2)) { sr[i] = -sr[i]; si[i] = -si[i]; }
                }
            }
        }
        float l0 = 0.f, l1 = 0.f;
        #pragma unroll
        for (int i = 0; i < 16; ++i) {
            float p = sr[i] * sr[i] + si[i] * si[i];
            l0 += (i & 8) ? -p : p;
            l1 += (i & 4) ? -p : p;
        }
        float m = fmaxf(l0, l1);
        float e0 = expf(l0 - m), e1 = expf(l1 - m);
        float inv = 1.f / (e0 + e1);
        out[b * 2 + 0] = e0 * inv;
        out[b * 2 + 1] = e1 * inv;
    }
}

extern "C" void kernel_launch(void* const* d_in, const int* in_sizes, int n_in,
                              void* d_out, int out_size, void* d_ws, size_t ws_size,
                              hipStream_t stream) {
    const float* x     = (const float*)d_in[0];
    const float* w1    = (const float*)d_in[1];
    const float* b1    = (const float*)d_in[2];
    const float* w2    = (const float*)d_in[3];
    const float* b2    = (const float*)d_in[4];
    const float* fc1_w = (const float*)d_in[5];
    const float* fc1_b = (const float*)d_in[6];
    const float* fc2_w = (const float*)d_in[7];
    const float* fc2_b = (const float*)d_in[8];
    const float* fc3_w = (const float*)d_in[9];
    const float* fc3_b = (const float*)d_in[10];
    const float* qw    = (const float*)d_in[11];
    float* out = (float*)d_out;

    // ws layout (all 256-B aligned):
    char* ws = (char*)d_ws;
    const size_t O_POOL1  = 0;                         // (B,6,123,128) bf16 = 48,365,568
    const size_t O_A      = O_POOL1 + 48365568;        // (256,KP) bf16     = 29,360,128
    const size_t O_W      = O_A + 29360128;            // (128,KP) bf16     = 14,680,064
    const size_t O_PART   = O_W + 14680064;            // (128,256,128) f32 = 16,777,216
    const size_t O_W1P    = O_PART + 16777216;         // 450 f32 (pad 2048)
    const size_t O_W2P    = O_W1P + 2048;              // 810 f32 (pad 4096)
    const size_t O_ZERO   = O_W2P + 4096;              // 256 B zeros
    unsigned short* pool1   = (unsigned short*)(ws + O_POOL1);
    __hip_bfloat16* A_bf16  = (__hip_bfloat16*)(ws + O_A);
    __hip_bfloat16* W_bf16  = (__hip_bfloat16*)(ws + O_W);
    float*          partial = (float*)(ws + O_PART);
    float*          w1p     = (float*)(ws + O_W1P);
    float*          w2p     = (float*)(ws + O_W2P);
    float*          zeros   = (float*)(ws + O_ZERO);

    prep_kernel<<<dim3(KP / 256, 128), 256, 0, stream>>>(
        w1, w2, fc1_w, w1p, w2p, zeros, (unsigned short*)W_bf16);
    conv1_pool1_kernel<<<dim3(18, B), 256, 0, stream>>>(x, w1p, b1, pool1, zeros);
    conv2_pool2_kernel<<<dim3(9, B), 128, 0, stream>>>(pool1, w2p, b2,
                                                       (unsigned short*)A_bf16,
                                                       (const unsigned int*)zeros);
    fc1_mfma_kernel<<<dim3(2, FC1_SPLIT), 256, 0, stream>>>(A_bf16, W_bf16, partial);
    tail_kernel<<<B, 256, 0, stream>>>(partial, fc1_b, fc2_w, fc2_b,
                                       fc3_w, fc3_b, qw, out);
}

// Round 3
// 421.400 us; speedup vs baseline: 1.0845x; 1.0481x over previous
//
#include <hip/hip_runtime.h>
#include <hip/hip_bf16.h>
#include <math.h>

// ---------------- dims ----------------
#define B 256
#define FC1_K   55815
#define FC1_N   120
#define FC2_N   84
#define KP        57344
#define FC1_SPLIT 256
#define FC1_KC    (KP / FC1_SPLIT)

typedef __attribute__((ext_vector_type(8))) short bf16x8;
typedef __attribute__((ext_vector_type(4))) float f32x4;

static __device__ __forceinline__ unsigned short bf16_bits(float f) {
    __hip_bfloat16 h = __float2bfloat16(f);
    return *(unsigned short*)&h;
}

// async global->LDS copy, 4 B per lane; lds base must be wave-uniform
#define ASYNC_CP(g, l) __builtin_amdgcn_global_load_lds( \
    (const __attribute__((address_space(1))) void*)(g),  \
    (__attribute__((address_space(3))) void*)(l), 4, 0, 0)

// ======== fused prep: conv-weight relayout + fc1_w->bf16 (incl. all pads) ===
// grid (KP/2048, 128): 8 elems/thread, vectorized bf16x8 stores.
__global__ __launch_bounds__(256) void prep_kernel(
    const float* __restrict__ w1, const float* __restrict__ w2,
    const float* __restrict__ fc1_w,
    float* __restrict__ w1p, float* __restrict__ w2p,
    float* __restrict__ zeros, unsigned short* __restrict__ wb) {
    const int n = blockIdx.y;                         // 0..127 (N-pad rows >=120)
    const int k0 = blockIdx.x * 2048 + threadIdx.x * 8;
    bf16x8 v8;
    #pragma unroll
    for (int i = 0; i < 8; ++i) v8[i] = 0;
    if (n < FC1_N) {
        const float* src = fc1_w + (size_t)n * FC1_K + k0;
        if (k0 + 8 <= FC1_K) {
            #pragma unroll
            for (int i = 0; i < 8; ++i) v8[i] = (short)bf16_bits(src[i]);
        } else {
            #pragma unroll
            for (int i = 0; i < 8; ++i)
                if (k0 + i < FC1_K) v8[i] = (short)bf16_bits(src[i]);
        }
    }
    *(bf16x8*)(wb + (size_t)n * KP + k0) = v8;

    if (blockIdx.x == 0 && n == 0) {
        int t = threadIdx.x;
        for (int f = t; f < 450; f += 256) {
            int o = f % 6, tap = f / 6;
            int kx = tap % 5, r2 = tap / 5, ky = r2 % 5, c = r2 / 5;
            w1p[f] = w1[(o * 3 + c) * 25 + ky * 5 + kx];
        }
        for (int f = t; f < 810; f += 256) {
            int o = f % 15, tap = f / 15;
            int kx = tap % 3, r2 = tap / 3, ky = r2 % 3, c = r2 / 3;
            w2p[f] = w2[(o * 6 + c) * 9 + ky * 3 + kx];
        }
        if (t < 64) zeros[t] = 0.f;                 // 256-B OOB source
    }
}

// ======== conv1 (5x5 s2 p1) + ReLU + pool(2,1) -> padded bf16 pool1 ========
// pool1 layout: (B, 6, 123, 128) bf16, col idx = px+1 (left pad), pads = 0.
// Block 256 = 32 colgroups x 8 conv rows. Grid (18 y-bands, 256 batch).
__global__ __launch_bounds__(256) void conv1_pool1_kernel(
    const float* __restrict__ x, const float* __restrict__ w1p,
    const float* __restrict__ b1, unsigned short* __restrict__ pool1,
    const float* __restrict__ zeros) {
    __shared__ __align__(16) float in_t[19 * 256 + 8];
    __shared__ __align__(16) unsigned short out_t[6 * 8 * 132];

    const int tid = threadIdx.x;
    const int wave = tid >> 6, lane = tid & 63;
    const int PB = 7 * blockIdx.x;          // pool row base
    const int b  = blockIdx.y;
    const int cg = tid & 31, rr = tid >> 5; // col group (4 cols), conv row 0..7
    const int iyb = 2 * PB - 1;

    float acc[4][6];
    #pragma unroll
    for (int j = 0; j < 4; ++j)
        #pragma unroll
        for (int o = 0; o < 6; ++o) acc[j][o] = b1[o];

    for (int c = 0; c < 3; ++c) {
        __syncthreads();                       // prev channel compute done
        const float* xp = x + (size_t)(b * 3 + c) * 62500;
        #pragma unroll
        for (int i = 0; i < 19; ++i) {
            int chunk = wave * 19 + i;         // 76 chunks of 64 floats
            int f = chunk * 64 + lane;
            int row = f >> 8, m = f & 255;
            int iy = iyb + row, col = m - 1;
            const float* g = ((unsigned)iy < 250u && (unsigned)col < 250u)
                             ? (xp + iy * 250 + col) : zeros;
            ASYNC_CP(g, &in_t[chunk * 64]);
        }
        __syncthreads();                       // drains vmcnt (async copies)
        const float* wc = w1p + c * 150;       // uniform -> s_load
        #pragma unroll
        for (int ky = 0; ky < 5; ++ky) {
            const float* rp = &in_t[(2 * rr + ky) * 256 + 8 * cg];
            float f[12];
            float4 v0 = *(const float4*)rp;
            float4 v1 = *(const float4*)(rp + 4);
            float4 v2 = *(const float4*)(rp + 8);
            f[0]=v0.x; f[1]=v0.y; f[2]=v0.z; f[3]=v0.w;
            f[4]=v1.x; f[5]=v1.y; f[6]=v1.z; f[7]=v1.w;
            f[8]=v2.x; f[9]=v2.y; f[10]=v2.z; f[11]=v2.w;
            #pragma unroll
            for (int kx = 0; kx < 5; ++kx) {
                const float* wp = wc + (ky * 5 + kx) * 6;  // uniform
                #pragma unroll
                for (int j = 0; j < 4; ++j) {
                    float xv = f[2 * j + kx];
                    #pragma unroll
                    for (int o = 0; o < 6; ++o) acc[j][o] += xv * wp[o];
                }
            }
        }
    }
    // write conv+ReLU tile as bf16
    #pragma unroll
    for (int o = 0; o < 6; ++o) {
        unsigned short h0 = bf16_bits(fmaxf(acc[0][o], 0.f));
        unsigned short h1 = bf16_bits(fmaxf(acc[1][o], 0.f));
        unsigned short h2 = bf16_bits(fmaxf(acc[2][o], 0.f));
        unsigned short h3 = bf16_bits(fmaxf(acc[3][o], 0.f));
        uint2 pk;
        pk.x = (unsigned)h0 | ((unsigned)h1 << 16);
        pk.y = (unsigned)h2 | ((unsigned)h3 << 16);
        *(uint2*)&out_t[(o * 8 + rr) * 132 + 4 * cg] = pk;
    }
    __syncthreads();
    // pool 2x2 s1 (integer max on non-negative bf16 bits), write padded pool1
    for (int it = tid; it < 6 * 7 * 32; it += 256) {
        int g = it & 31, rem = it >> 5;
        int pyl = rem % 7, oc = rem / 7;
        int py = PB + pyl;
        if (py >= 123) continue;
        const unsigned short* q0 = &out_t[(oc * 8 + pyl) * 132 + 4 * g];
        const unsigned short* q1 = q0 + 132;
        uint2 ua = *(const uint2*)q0;
        uint2 ub = *(const uint2*)q1;
        unsigned short va[5] = {(unsigned short)(ua.x & 0xffff), (unsigned short)(ua.x >> 16),
                                (unsigned short)(ua.y & 0xffff), (unsigned short)(ua.y >> 16), q0[4]};
        unsigned short vb[5] = {(unsigned short)(ub.x & 0xffff), (unsigned short)(ub.x >> 16),
                                (unsigned short)(ub.y & 0xffff), (unsigned short)(ub.y >> 16), q1[4]};
        unsigned short* dst = pool1 + ((size_t)(b * 6 + oc) * 123 + py) * 128;
        #pragma unroll
        for (int j = 0; j < 4; ++j) {
            int px = 4 * g + j;
            if (px >= 127) continue;
            unsigned short m = 0;
            if (px <= 122) {
                unsigned short m0 = va[j] > va[j+1] ? va[j] : va[j+1];
                unsigned short m1 = vb[j] > vb[j+1] ? vb[j] : vb[j+1];
                m = m0 > m1 ? m0 : m1;
            }
            dst[1 + px] = m;
        }
        if (g == 0) dst[0] = 0;
    }
}

// ======== conv2 (3x3 s2 p1) + ReLU + pool(2,1) -> bf16 A rows ========
// Block 128 = 16 colgroups x 8 conv rows. Grid (9 y-bands, 256 batch).
__global__ __launch_bounds__(128) void conv2_pool2_kernel(
    const unsigned short* __restrict__ pool1, const float* __restrict__ w2p,
    const float* __restrict__ b2, unsigned short* __restrict__ A,
    const unsigned int* __restrict__ zerosu) {
    __shared__ __align__(16) unsigned int in2[17 * 64 + 4];
    __shared__ __align__(16) unsigned short out2[15 * 8 * 68];

    const int tid = threadIdx.x;
    const int wave = tid >> 6, lane = tid & 63;
    const int PB = 7 * blockIdx.x;
    const int b  = blockIdx.y;
    const int cg = tid & 15, rr = tid >> 4;
    const int iyb = 2 * PB - 1;

    float acc[4][15];
    #pragma unroll
    for (int j = 0; j < 4; ++j)
        #pragma unroll
        for (int o = 0; o < 15; ++o) acc[j][o] = b2[o];

    const unsigned int* p1u = (const unsigned int*)pool1;
    for (int c = 0; c < 6; ++c) {
        __syncthreads();
        const unsigned int* pp = p1u + (size_t)(b * 6 + c) * (123 * 64);
        #pragma unroll
        for (int i = 0; i < 9; ++i) {
            int chunk = wave * 9 + i;          // 17 chunks of 64 u32
            if (chunk < 17) {
                int f = chunk * 64 + lane;
                int row = f >> 6, off = f & 63;
                int iy = iyb + row;
                const unsigned int* g = ((unsigned)iy < 123u)
                                        ? (pp + iy * 64 + off) : zerosu;
                ASYNC_CP(g, &in2[chunk * 64]);
            }
        }
        __syncthreads();
        #pragma unroll
        for (int ky = 0; ky < 3; ++ky) {
            const unsigned int* rp = &in2[(2 * rr + ky) * 64 + 4 * cg];
            uint4 u4 = *(const uint4*)rp;
            unsigned int u5 = rp[4];
            float f[10];
            f[0] = __uint_as_float(u4.x << 16); f[1] = __uint_as_float(u4.x & 0xffff0000u);
            f[2] = __uint_as_float(u4.y << 16); f[3] = __uint_as_float(u4.y & 0xffff0000u);
            f[4] = __uint_as_float(u4.z << 16); f[5] = __uint_as_float(u4.z & 0xffff0000u);
            f[6] = __uint_as_float(u4.w << 16); f[7] = __uint_as_float(u4.w & 0xffff0000u);
            f[8] = __uint_as_float(u5  << 16);  f[9] = __uint_as_float(u5  & 0xffff0000u);
            #pragma unroll
            for (int kx = 0; kx < 3; ++kx) {
                const float* wp = w2p + (c * 9 + ky * 3 + kx) * 15;  // uniform
                #pragma unroll
                for (int j = 0; j < 4; ++j) {
                    float xv = f[2 * j + kx];
                    #pragma unroll
                    for (int o = 0; o < 15; ++o) acc[j][o] += xv * wp[o];
                }
            }
        }
    }
    #pragma unroll
    for (int o = 0; o < 15; ++o) {
        unsigned short h0 = bf16_bits(fmaxf(acc[0][o], 0.f));
        unsigned short h1 = bf16_bits(fmaxf(acc[1][o], 0.f));
        unsigned short h2 = bf16_bits(fmaxf(acc[2][o], 0.f));
        unsigned short h3 = bf16_bits(fmaxf(acc[3][o], 0.f));
        uint2 pk;
        pk.x = (unsigned)h0 | ((unsigned)h1 << 16);
        pk.y = (unsigned)h2 | ((unsigned)h3 << 16);
        *(uint2*)&out2[(o * 8 + rr) * 68 + 4 * cg] = pk;
    }
    __syncthreads();
    for (int it = tid; it < 15 * 7 * 16; it += 128) {
        int g = it & 15, rem = it >> 4;
        int pyl = rem % 7, oc = rem / 7;
        int py = PB + pyl;
        if (py >= 61) continue;
        const unsigned short* q0 = &out2[(oc * 8 + pyl) * 68 + 4 * g];
        const unsigned short* q1 = q0 + 68;
        uint2 ua = *(const uint2*)q0;
        uint2 ub = *(const uint2*)q1;
        unsigned short va[5] = {(unsigned short)(ua.x & 0xffff), (unsigned short)(ua.x >> 16),
                                (unsigned short)(ua.y & 0xffff), (unsigned short)(ua.y >> 16), q0[4]};
        unsigned short vb[5] = {(unsigned short)(ub.x & 0xffff), (unsigned short)(ub.x >> 16),
                                (unsigned short)(ub.y & 0xffff), (unsigned short)(ub.y >> 16), q1[4]};
        #pragma unroll
        for (int j = 0; j < 4; ++j) {
            int px = 4 * g + j;
            if (px < 61) {
                unsigned short m0 = va[j] > va[j+1] ? va[j] : va[j+1];
                unsigned short m1 = vb[j] > vb[j+1] ? vb[j] : vb[j+1];
                unsigned short m = m0 > m1 ? m0 : m1;
                A[(size_t)b * KP + (oc * 61 + py) * 61 + px] = m;
            }
        }
    }
}

// ================= fc1: bf16 MFMA split-K GEMM -> fp32 partials ===========
// SPLIT=256 -> 512 blocks = 2 blocks/CU (2 waves/SIMD of TLP).
__global__ __launch_bounds__(256) void fc1_mfma_kernel(
    const __hip_bfloat16* __restrict__ A, const __hip_bfloat16* __restrict__ W,
    float* __restrict__ partial) {
    const int wave = threadIdx.x >> 6, lane = threadIdx.x & 63;
    const int mrow = lane & 15, quad = lane >> 4;
    const int m0 = blockIdx.x * 128 + wave * 32;
    const int k0 = blockIdx.y * FC1_KC;

    f32x4 acc[2][8];
    #pragma unroll
    for (int i = 0; i < 2; ++i)
        #pragma unroll
        for (int j = 0; j < 8; ++j) acc[i][j] = (f32x4){0.f, 0.f, 0.f, 0.f};

    const short* Ap = (const short*)A;
    const short* Wp = (const short*)W;
    for (int ks = 0; ks < FC1_KC; ks += 32) {
        const int kk = k0 + ks + quad * 8;
        const bf16x8 a0 = *(const bf16x8*)(Ap + (size_t)(m0 + mrow) * KP + kk);
        const bf16x8 a1 = *(const bf16x8*)(Ap + (size_t)(m0 + 16 + mrow) * KP + kk);
        #pragma unroll
        for (int nt = 0; nt < 8; ++nt) {
            const bf16x8 bb = *(const bf16x8*)(Wp + (size_t)(nt * 16 + mrow) * KP + kk);
            acc[0][nt] = __builtin_amdgcn_mfma_f32_16x16x32_bf16(a0, bb, acc[0][nt], 0, 0, 0);
            acc[1][nt] = __builtin_amdgcn_mfma_f32_16x16x32_bf16(a1, bb, acc[1][nt], 0, 0, 0);
        }
    }
    float* po = partial + (size_t)blockIdx.y * (256 * 128);
    #pragma unroll
    for (int mt = 0; mt < 2; ++mt)
        #pragma unroll
        for (int nt = 0; nt < 8; ++nt)
            #pragma unroll
            for (int r = 0; r < 4; ++r)
                po[(m0 + mt * 16 + quad * 4 + r) * 128 + nt * 16 + mrow] = acc[mt][nt][r];
}

// ====== tail: split-K reduce + bias/ReLU, fc2, fc3, quantum head, softmax ==
// 512 threads: 4-way parallel split-K reduce; quantum head wave-parallel on
// lanes 0..15 (amp i on lane i), gates via shfl_xor, fast __sinf/__cosf.
__global__ __launch_bounds__(512) void tail_kernel(
    const float* __restrict__ partial, const float* __restrict__ fc1_b,
    const float* __restrict__ fc2_w, const float* __restrict__ fc2_b,
    const float* __restrict__ fc3_w, const float* __restrict__ fc3_b,
    const float* __restrict__ qw, float* __restrict__ out) {
    __shared__ float h1p[4][FC1_N];
    __shared__ float h1[FC1_N];
    __shared__ float h2[FC2_N];
    __shared__ float ang[4];
    int b = blockIdx.x;
    int t = threadIdx.x;
    int grp = t >> 7, tt = t & 127;

    if (tt < FC1_N) {
        const float* p = partial + b * 128 + tt;
        float sum = 0.f;
        #pragma unroll 8
        for (int s = grp * 64; s < grp * 64 + 64; ++s) sum += p[(size_t)s * (256 * 128)];
        h1p[grp][tt] = sum;
    }
    __syncthreads();
    if (t < FC1_N)
        h1[t] = fmaxf(h1p[0][t] + h1p[1][t] + h1p[2][t] + h1p[3][t] + fc1_b[t], 0.f);
    __syncthreads();
    if (t < FC2_N) {
        float acc = fc2_b[t];
        const float* w = fc2_w + t * FC1_N;
        for (int k = 0; k < FC1_N; ++k) acc += h1[k] * w[k];
        h2[t] = fmaxf(acc, 0.f);
    }
    __syncthreads();
    if (t < 4) {
        float acc = fc3_b[t];
        const float* w = fc3_w + t * FC2_N;
        for (int k = 0; k < FC2_N; ++k) acc += h2[k] * w[k];
        ang[t] = acc;
    }
    __syncthreads();
    if (t < 16) {
        const int lane = t;
        float sr = (lane == 0) ? 1.f : 0.f, si = 0.f;
        // RX encoding: same update formula for both parities
        #pragma unroll
        for (int q = 0; q < 4; ++q) {
            float th = ang[q] * 0.5f;
            float c = __cosf(th), s = __sinf(th);
            int mask = 8 >> q;
            float pr = __shfl_xor(sr, mask, 16);
            float pi = __shfl_xor(si, mask, 16);
            float nr = c * sr + s * pi;
            float ni = c * si - s * pr;
            sr = nr; si = ni;
        }
        int widx = 0;
        #pragma unroll
        for (int d = 0; d < 2; ++d) {
            #pragma unroll
            for (int q = 0; q < 4; ++q) {
                float th = qw[widx++] * 0.5f;
                float c = __cosf(th), s = __sinf(th);
                int mask = 8 >> q;
                float pr = __shfl_xor(sr, mask, 16);
                float pi = __shfl_xor(si, mask, 16);
                float sg = (lane & mask) ? s : -s;   // RY: sign depends on parity
                sr = c * sr + sg * pr;
                si = c * si + sg * pi;
            }
            #pragma unroll
            for (int q = 0; q < 3; ++q) {
                int m1 = 8 >> q, m2 = 4 >> q;
                if ((lane & m1) && (lane & m2)) { sr = -sr; si = -si; }
            }
        }
        float p = sr * sr + si * si;
        float v0 = (lane & 8) ? -p : p;
        float v1 = (lane & 4) ? -p : p;
        #pragma unroll
        for (int off = 8; off >= 1; off >>= 1) {
            v0 += __shfl_xor(v0, off, 16);
            v1 += __shfl_xor(v1, off, 16);
        }
        if (lane == 0) {
            float m = fmaxf(v0, v1);
            float e0 = expf(v0 - m), e1 = expf(v1 - m);
            float inv = 1.f / (e0 + e1);
            out[b * 2 + 0] = e0 * inv;
            out[b * 2 + 1] = e1 * inv;
        }
    }
}

extern "C" void kernel_launch(void* const* d_in, const int* in_sizes, int n_in,
                              void* d_out, int out_size, void* d_ws, size_t ws_size,
                              hipStream_t stream) {
    const float* x     = (const float*)d_in[0];
    const float* w1    = (const float*)d_in[1];
    const float* b1    = (const float*)d_in[2];
    const float* w2    = (const float*)d_in[3];
    const float* b2    = (const float*)d_in[4];
    const float* fc1_w = (const float*)d_in[5];
    const float* fc1_b = (const float*)d_in[6];
    const float* fc2_w = (const float*)d_in[7];
    const float* fc2_b = (const float*)d_in[8];
    const float* fc3_w = (const float*)d_in[9];
    const float* fc3_b = (const float*)d_in[10];
    const float* qw    = (const float*)d_in[11];
    float* out = (float*)d_out;

    // ws layout (all 256-B aligned):
    char* ws = (char*)d_ws;
    const size_t O_POOL1  = 0;                         // (B,6,123,128) bf16 = 48,365,568
    const size_t O_A      = O_POOL1 + 48365568;        // (256,KP) bf16     = 29,360,128
    const size_t O_W      = O_A + 29360128;            // (128,KP) bf16     = 14,680,064
    const size_t O_PART   = O_W + 14680064;            // (256,256,128) f32 = 33,554,432
    const size_t O_W1P    = O_PART + 33554432;         // 450 f32 (pad 2048)
    const size_t O_W2P    = O_W1P + 2048;              // 810 f32 (pad 4096)
    const size_t O_ZERO   = O_W2P + 4096;              // 256 B zeros
    unsigned short* pool1   = (unsigned short*)(ws + O_POOL1);
    __hip_bfloat16* A_bf16  = (__hip_bfloat16*)(ws + O_A);
    __hip_bfloat16* W_bf16  = (__hip_bfloat16*)(ws + O_W);
    float*          partial = (float*)(ws + O_PART);
    float*          w1p     = (float*)(ws + O_W1P);
    float*          w2p     = (float*)(ws + O_W2P);
    float*          zeros   = (float*)(ws + O_ZERO);

    prep_kernel<<<dim3(KP / 2048, 128), 256, 0, stream>>>(
        w1, w2, fc1_w, w1p, w2p, zeros, (unsigned short*)W_bf16);
    conv1_pool1_kernel<<<dim3(18, B), 256, 0, stream>>>(x, w1p, b1, pool1, zeros);
    conv2_pool2_kernel<<<dim3(9, B), 128, 0, stream>>>(pool1, w2p, b2,
                                                       (unsigned short*)A_bf16,
                                                       (const unsigned int*)zeros);
    fc1_mfma_kernel<<<dim3(2, FC1_SPLIT), 256, 0, stream>>>(A_bf16, W_bf16, partial);
    tail_kernel<<<B, 512, 0, stream>>>(partial, fc1_b, fc2_w, fc2_b,
                                       fc3_w, fc3_b, qw, out);
}